// Round 7
// baseline (169.675 us; speedup 1.0000x reference)
//
#include <hip/hip_runtime.h>

#define SEQ_LEN 262144
#define K 512                      // steps per group (one wave per group)
#define M 8                        // steps per lane
#define NG (SEQ_LEN / K)           // 512 groups
#define WPB 8                      // waves per block
#define NB (NG / WPB)              // 64 blocks
#define HID 256
#define C2LE 2.885390081777927f    // 2*log2(e)
// NCORR structure fixed at 2: phase0 (first shoot), phase1 (correct+shoot), phase2 (correct+shoot+store)
// (NCORR=1 FAILS: absmax 3.6e-2 measured in prior session R11)
//
// R2: cg::grid.sync + per-wave __threadfence = ~200us L2 maintenance storm.
// R3: launch_bounds(256,2) -> 128-VGPR cap -> scratch spill; coop launch +95us.
// R4: 512x64 + sc1 exchange + counter barrier -> 76us kernel, VALUBusy 5%.
// R5: backoff polling + 8B jf + fused MLP -> 82us kernel. ~60us stall =
//     ARRIVAL serialization (512 same-line atomic RMWs x ~140cyc x 2 barriers).
// R6: 64 blocks x 512 thr cut arrivals 8x, BUT __launch_bounds__(512) without
//     min-waves arg -> compiler capped 128 VGPR -> spill returned (WRITE 16.4MB
//     vs 6.4MB real, FETCH 6.9MB vs 2.0MB) -> 104us. Barrier win < spill loss.
// R7: __launch_bounds__(512, 2): 2 waves/EU min -> 256-VGPR cap -> no spill,
//     8 waves/block = 2/SIMD = 1 block/CU, 64 blocks co-resident. Sole change.

// ---------- DPP helpers ----------
template <int CTRL, int RM>
__device__ __forceinline__ float dpp_mov(float oldv, float v) {
    return __builtin_bit_cast(float, __builtin_amdgcn_update_dpp(
        __builtin_bit_cast(int, oldv), __builtin_bit_cast(int, v), CTRL, RM, 0xf, false));
}
template <int CTRL, int RM>
__device__ __forceinline__ float dpp_add(float v) {
    return v + dpp_mov<CTRL, RM>(0.0f, v);
}
__device__ __forceinline__ float wave_incl_scan(float v) {
    v = dpp_add<0x111, 0xf>(v);
    v = dpp_add<0x112, 0xf>(v);
    v = dpp_add<0x114, 0xf>(v);
    v = dpp_add<0x118, 0xf>(v);
    v = dpp_add<0x142, 0xa>(v);
    v = dpp_add<0x143, 0xc>(v);
    return v;
}
// full-wave shift right by 1 (lane i <- lane i-1; lane 0 <- 0)
__device__ __forceinline__ float dpp_wshr1(float v) {
    return __builtin_bit_cast(float, __builtin_amdgcn_update_dpp(
        0, __builtin_bit_cast(int, v), 0x138, 0xf, 0xf, false));
}
__device__ __forceinline__ float readlane_f(float v, int lane) {
    return __builtin_bit_cast(
        float, __builtin_amdgcn_readlane(__builtin_bit_cast(int, v), lane));
}

// ---------- agent-scope coherent access (sc1 -> LLC-coherent, bypasses per-XCD L2) ----------
typedef unsigned long long u64t;
__device__ __forceinline__ float2 coh_load_f2(const float* p) {
    u64t v = __hip_atomic_load((const u64t*)p, __ATOMIC_RELAXED, __HIP_MEMORY_SCOPE_AGENT);
    return __builtin_bit_cast(float2, v);
}
__device__ __forceinline__ void coh_store_f2(float* p, float a, float b) {
    float2 t{a, b};
    __hip_atomic_store((u64t*)p, __builtin_bit_cast(u64t, t),
                       __ATOMIC_RELAXED, __HIP_MEMORY_SCOPE_AGENT);
}

// ---------- block-cooperative grid barrier ----------
// One atomic arrival per BLOCK (64 total). Release = per-wave s_waitcnt vmcnt(0)
// (sc1 stores are LLC-coherent once drained) + __syncthreads collect, then tid0
// arrives + polls, __syncthreads releases the other 7 waves (they sleep at the
// block barrier -> zero LLC pressure).
__device__ __forceinline__ void gbar(unsigned* ctr, unsigned target) {
    asm volatile("s_waitcnt vmcnt(0) lgkmcnt(0)" ::: "memory");
    __syncthreads();
    if (threadIdx.x == 0) {
        __hip_atomic_fetch_add(ctr, 1u, __ATOMIC_RELAXED, __HIP_MEMORY_SCOPE_AGENT);
        while (__hip_atomic_load(ctr, __ATOMIC_RELAXED, __HIP_MEMORY_SCOPE_AGENT) < target)
            __builtin_amdgcn_s_sleep(16);   // ~0.4us granularity, 64 pollers only
    }
    __syncthreads();
    asm volatile("" ::: "memory");   // keep jf loads after the release
}

// ---------- affine map (3x3 M, 3 b) ----------
struct Aff { float m[9]; float b[3]; };

// r = n ∘ o  (apply o first, then n)
__device__ __forceinline__ void compose(Aff& r, const Aff& n, const Aff& o) {
#pragma unroll
    for (int i = 0; i < 3; ++i) {
#pragma unroll
        for (int j = 0; j < 3; ++j)
            r.m[3*i+j] = fmaf(n.m[3*i+0], o.m[0+j],
                         fmaf(n.m[3*i+1], o.m[3+j],
                              n.m[3*i+2] * o.m[6+j]));
        r.b[i] = fmaf(n.m[3*i+0], o.b[0],
                 fmaf(n.m[3*i+1], o.b[1],
                 fmaf(n.m[3*i+2], o.b[2], n.b[i])));
    }
}

template <int CTRL, int RM>
__device__ __forceinline__ void scan_level(Aff& a) {
    Aff p;
    p.m[0] = dpp_mov<CTRL, RM>(1.f, a.m[0]);
    p.m[1] = dpp_mov<CTRL, RM>(0.f, a.m[1]);
    p.m[2] = dpp_mov<CTRL, RM>(0.f, a.m[2]);
    p.m[3] = dpp_mov<CTRL, RM>(0.f, a.m[3]);
    p.m[4] = dpp_mov<CTRL, RM>(1.f, a.m[4]);
    p.m[5] = dpp_mov<CTRL, RM>(0.f, a.m[5]);
    p.m[6] = dpp_mov<CTRL, RM>(0.f, a.m[6]);
    p.m[7] = dpp_mov<CTRL, RM>(0.f, a.m[7]);
    p.m[8] = dpp_mov<CTRL, RM>(1.f, a.m[8]);
    p.b[0] = dpp_mov<CTRL, RM>(0.f, a.b[0]);
    p.b[1] = dpp_mov<CTRL, RM>(0.f, a.b[1]);
    p.b[2] = dpp_mov<CTRL, RM>(0.f, a.b[2]);
    Aff r; compose(r, a, p); a = r;
}

// ===================================================================
// MODE: 0 = FIRST (x0=0, no correct, write jf)
//       1 = MID   (correct with xh_old==0, SAVE xh_new to xk regs, shoot, write jf)
//       2 = FINAL (correct from jf_r + xk regs, shoot, store xs, fused MLP -> out)
// xh carried in registers between phases: phase-1's correction scan computes
// ALL groups' corrected start states redundantly in every wave, so phase-2's
// xh_old[g+1] is already in this lane's registers (bit-identical everywhere).
// ===================================================================
template <int MODE>
__device__ __forceinline__ void shoot_phase(
    const int lane, const int g, const int base,
    const float dt, const float invdt3,
    const float (&a)[9], const float (&as)[9],
    const float (&w0)[M], const float (&w1)[M], const float (&w2)[M],
    const float4* __restrict__ jf_r, float4* __restrict__ jf_w,
    float (&xk0)[8], float (&xk1)[8], float (&xk2)[8],
    float* __restrict__ xs,
    const float4* lw1i, const float4* lw2i,          // LDS weight tables (MODE 2)
    const float* __restrict__ b2v, float* __restrict__ out) {

    // ---- Newton correct (redundant per wave) -> this group's start state ----
    float x0 = 0.f, x1 = 0.f, x2 = 0.f;
    if (MODE != 0) {
        float J[8][9], dv[8][3], xhn0[8], xhn1[8], xhn2[8];
#pragma unroll
        for (int i = 0; i < 8; ++i) {
            int gg = 8 * lane + i;
            // coherent 8B loads: written by waves on other XCDs; also defeats
            // stale L2 lines from previous graph replays.
            const float* src = (const float*)(jf_r + 3 * gg);
            float2 v0 = coh_load_f2(src + 0), v1 = coh_load_f2(src + 2),
                   v2 = coh_load_f2(src + 4), v3 = coh_load_f2(src + 6),
                   v4 = coh_load_f2(src + 8), v5 = coh_load_f2(src + 10);
            J[i][0] = v0.x; J[i][1] = v0.y; J[i][2] = v1.x;
            J[i][3] = v1.y; J[i][4] = v2.x; J[i][5] = v2.y;
            J[i][6] = v3.x; J[i][7] = v3.y; J[i][8] = v4.x;
            float xn0 = 0.f, xn1 = 0.f, xn2 = 0.f;
            if (MODE == 2) { xn0 = xk0[i]; xn1 = xk1[i]; xn2 = xk2[i]; }
            xhn0[i] = xn0; xhn1[i] = xn1; xhn2[i] = xn2;
            dv[i][0] = v4.y - xn0;               // F_g - xh_old[g+1]
            dv[i][1] = v5.x - xn1;
            dv[i][2] = v5.y - xn2;
        }
        Aff c;
#pragma unroll
        for (int k = 0; k < 9; ++k) c.m[k] = J[0][k];
        c.b[0] = dv[0][0]; c.b[1] = dv[0][1]; c.b[2] = dv[0][2];
#pragma unroll
        for (int i = 1; i < 8; ++i) {
            Aff s;
#pragma unroll
            for (int k = 0; k < 9; ++k) s.m[k] = J[i][k];
            s.b[0] = dv[i][0]; s.b[1] = dv[i][1]; s.b[2] = dv[i][2];
            Aff r; compose(r, s, c); c = r;
        }
        scan_level<0x111, 0xf>(c);
        scan_level<0x112, 0xf>(c);
        scan_level<0x114, 0xf>(c);
        scan_level<0x118, 0xf>(c);
        scan_level<0x142, 0xa>(c);
        scan_level<0x143, 0xc>(c);
        float ce0 = dpp_wshr1(c.b[0]);           // e at group 8*lane
        float ce1 = dpp_wshr1(c.b[1]);
        float ce2 = dpp_wshr1(c.b[2]);
        // walk: e_{g+1} = d_g + J_g e_g ; xh_new[g+1] = xh_old[g+1] + e_{g+1}
#pragma unroll
        for (int i = 0; i < 8; ++i) {
            float n0 = fmaf(J[i][0], ce0, fmaf(J[i][1], ce1, fmaf(J[i][2], ce2, dv[i][0])));
            float n1 = fmaf(J[i][3], ce0, fmaf(J[i][4], ce1, fmaf(J[i][5], ce2, dv[i][1])));
            float n2 = fmaf(J[i][6], ce0, fmaf(J[i][7], ce1, fmaf(J[i][8], ce2, dv[i][2])));
            ce0 = n0; ce1 = n1; ce2 = n2;
            xhn0[i] += ce0; xhn1[i] += ce1; xhn2[i] += ce2;  // now xh_new[8l+i+1]
        }
        if (MODE == 1) {   // carry corrected start states to phase 2 in registers
#pragma unroll
            for (int i = 0; i < 8; ++i) { xk0[i] = xhn0[i]; xk1[i] = xhn1[i]; xk2[i] = xhn2[i]; }
        }
        // broadcast xh_new[g] to the whole wave (g>0; g==0 stays 0)
        if (g > 0) {
            const int tl = (g - 1) >> 3, idx = (g - 1) & 7;  // wave-uniform
            float p0 = xhn0[0], p1 = xhn1[0], p2 = xhn2[0];
#pragma unroll
            for (int i = 1; i < 8; ++i) {
                p0 = (idx == i) ? xhn0[i] : p0;
                p1 = (idx == i) ? xhn1[i] : p1;
                p2 = (idx == i) ? xhn2[i] : p2;
            }
            x0 = readlane_f(p0, tl);
            x1 = readlane_f(p1, tl);
            x2 = readlane_f(p2, tl);
        }
    }

    // ---- shoot body (validated scheme, unchanged math) ----
    float zc0 = fmaf(as[0], x0, fmaf(as[1], x1, as[2] * x2));
    float zc1 = fmaf(as[3], x0, fmaf(as[4], x1, as[5] * x2));
    float zc2 = fmaf(as[6], x0, fmaf(as[7], x1, as[8] * x2));

    float t0s[M][3], c1s[M][3];
    Aff acc;
#pragma unroll
    for (int i = 0; i < M; ++i) {
        float z[3] = { w0[i] + zc0, w1[i] + zc1, w2[i] + zc2 };
        float cb[3], cv[3];
#pragma unroll
        for (int c = 0; c < 3; ++c) {
            float e  = __builtin_amdgcn_exp2f(z[c]);
            float r  = __builtin_amdgcn_rcpf(e + 1.0f);
            float t  = fmaf(-2.0f, r, 1.0f);
            float b  = dt * t;
            float c1 = fmaf(-b, t, dt);
            t0s[i][c] = t; c1s[i][c] = c1;
            cb[c] = b; cv[c] = c1;
        }
        Aff s;
        s.m[0] = fmaf(cv[0], a[0], 1.f); s.m[1] = cv[0] * a[1]; s.m[2] = cv[0] * a[2];
        s.m[3] = cv[1] * a[3]; s.m[4] = fmaf(cv[1], a[4], 1.f); s.m[5] = cv[1] * a[5];
        s.m[6] = cv[2] * a[6]; s.m[7] = cv[2] * a[7]; s.m[8] = fmaf(cv[2], a[8], 1.f);
        s.b[0] = cb[0]; s.b[1] = cb[1]; s.b[2] = cb[2];
        if (i == 0) acc = s;
        else { Aff r; compose(r, s, acc); acc = r; }
    }

    scan_level<0x111, 0xf>(acc);
    scan_level<0x112, 0xf>(acc);
    scan_level<0x114, 0xf>(acc);
    scan_level<0x118, 0xf>(acc);
    scan_level<0x142, 0xa>(acc);
    scan_level<0x143, 0xc>(acc);

    float ds0 = dpp_wshr1(acc.b[0]);
    float ds1 = dpp_wshr1(acc.b[1]);
    float ds2 = dpp_wshr1(acc.b[2]);

    float d0 = ds0, d1 = ds1, d2 = ds2;
    float outv[M][3];
#pragma unroll
    for (int i = 0; i < M; ++i) {
        float zz0 = fmaf(a[0], d0, fmaf(a[1], d1, a[2] * d2));
        float zz1 = fmaf(a[3], d0, fmaf(a[4], d1, a[5] * d2));
        float zz2 = fmaf(a[6], d0, fmaf(a[7], d1, a[8] * d2));
        float zz[3] = { zz0, zz1, zz2 };
        float dd[3];
#pragma unroll
        for (int c = 0; c < 3; ++c) {
            float t   = t0s[i][c], cv = c1s[i][c];
            float cb  = dt * t;
            float cT2 = -(t * cv);
            float pc  = fmaf(-invdt3, cv, 0.66666667f * (t * t));
            float cT3 = cv * pc;
            dd[c] = fmaf(fmaf(fmaf(cT3, zz[c], cT2), zz[c], cv), zz[c], cb);
        }
        d0 += dd[0]; d1 += dd[1]; d2 += dd[2];
        outv[i][0] = d0; outv[i][1] = d1; outv[i][2] = d2;
    }

    float q0 = d0 - acc.b[0], q1 = d1 - acc.b[1], q2 = d2 - acc.b[2];
    float e0 = wave_incl_scan(q0) - q0;
    float e1 = wave_incl_scan(q1) - q1;
    float e2 = wave_incl_scan(q2) - q2;
    float cor0 = x0 + e0, cor1 = x1 + e1, cor2 = x2 + e2;

    if (MODE == 2) {
        // final membrane values for this lane's 8 steps (also the MLP inputs)
        float X0[M], X1[M], X2[M];
#pragma unroll
        for (int i = 0; i < M; ++i) {
            X0[i] = outv[i][0] + cor0;
            X1[i] = outv[i][1] + cor1;
            X2[i] = outv[i][2] + cor2;
        }
        *(float4*)&xs[base]                   = float4{ X0[0], X0[1], X0[2], X0[3] };
        *(float4*)&xs[base + 4]               = float4{ X0[4], X0[5], X0[6], X0[7] };
        *(float4*)&xs[SEQ_LEN + base]         = float4{ X1[0], X1[1], X1[2], X1[3] };
        *(float4*)&xs[SEQ_LEN + base + 4]     = float4{ X1[4], X1[5], X1[6], X1[7] };
        *(float4*)&xs[2 * SEQ_LEN + base]     = float4{ X2[0], X2[1], X2[2], X2[3] };
        *(float4*)&xs[2 * SEQ_LEN + base + 4] = float4{ X2[4], X2[5], X2[6], X2[7] };

        // ---- fused MLP on register data; weights from LDS float4 tables ----
        // (uniform h across lanes -> LDS broadcast reads, conflict-free)
        float O0[M], O1[M], O2[M];
#pragma unroll
        for (int i = 0; i < M; ++i) { O0[i] = 0.f; O1[i] = 0.f; O2[i] = 0.f; }
#pragma unroll 2
        for (int h = 0; h < HID; ++h) {
            float4 wb = lw1i[h];   // {W1[h][0], W1[h][1], W1[h][2], b1[h]}
            float4 qv = lw2i[h];   // {W2[0][h], W2[1][h], W2[2][h], 0}
#pragma unroll
            for (int i = 0; i < M; ++i) {
                float hv = fmaf(wb.x, X0[i], fmaf(wb.y, X1[i], fmaf(wb.z, X2[i], wb.w)));
                hv = fmaxf(hv, 0.f);
                O0[i] = fmaf(qv.x, hv, O0[i]);
                O1[i] = fmaf(qv.y, hv, O1[i]);
                O2[i] = fmaf(qv.z, hv, O2[i]);
            }
        }
        const float bb0 = b2v[0], bb1 = b2v[1], bb2 = b2v[2];
        *(float4*)&out[base]                   = float4{ O0[0]+bb0, O0[1]+bb0, O0[2]+bb0, O0[3]+bb0 };
        *(float4*)&out[base + 4]               = float4{ O0[4]+bb0, O0[5]+bb0, O0[6]+bb0, O0[7]+bb0 };
        *(float4*)&out[SEQ_LEN + base]         = float4{ O1[0]+bb1, O1[1]+bb1, O1[2]+bb1, O1[3]+bb1 };
        *(float4*)&out[SEQ_LEN + base + 4]     = float4{ O1[4]+bb1, O1[5]+bb1, O1[6]+bb1, O1[7]+bb1 };
        *(float4*)&out[2 * SEQ_LEN + base]     = float4{ O2[0]+bb2, O2[1]+bb2, O2[2]+bb2, O2[3]+bb2 };
        *(float4*)&out[2 * SEQ_LEN + base + 4] = float4{ O2[4]+bb2, O2[5]+bb2, O2[6]+bb2, O2[7]+bb2 };
    } else {
        if (lane == 63) {
            float F0 = outv[M-1][0] + cor0;
            float F1 = outv[M-1][1] + cor1;
            float F2 = outv[M-1][2] + cor2;
            float* dst = (float*)(jf_w + 3 * g);
            coh_store_f2(dst + 0,  acc.m[0], acc.m[1]);
            coh_store_f2(dst + 2,  acc.m[2], acc.m[3]);
            coh_store_f2(dst + 4,  acc.m[4], acc.m[5]);
            coh_store_f2(dst + 6,  acc.m[6], acc.m[7]);
            coh_store_f2(dst + 8,  acc.m[8], F0);
            coh_store_f2(dst + 10, F1, F2);
        }
    }
}

// ---------- single fused kernel: 64 blocks x 512 threads, plain launch ----------
// __launch_bounds__(512, 2): 2 waves/EU min -> 256-VGPR cap (live set ~200, no
// spill). 8 waves/block = 2/SIMD = 1 block/CU; 64 blocks trivially co-resident,
// so the counter barrier cannot deadlock. Wave w handles group blockIdx*8+w.
__global__ __launch_bounds__(512, 2) void shoot_fused_mlp(
    const float* __restrict__ u,     // [3][S]
    const float* __restrict__ Am,    // [3][3]
    const float* __restrict__ dtp,   // scalar
    const float* __restrict__ Bm,    // [3][3]
    const float* __restrict__ bAp,   // [3]
    const float* __restrict__ W1,    // [256][3]
    const float* __restrict__ b1v,   // [256]
    const float* __restrict__ W2,    // [3][256]
    const float* __restrict__ b2v,   // [3]
    float4* __restrict__ jfA,        // [NG*3]
    float4* __restrict__ jfB,        // [NG*3]
    unsigned* __restrict__ ctr,      // grid-barrier counter (memset 0 per launch)
    float* __restrict__ xs,          // [3][S] membrane out
    float* __restrict__ out) {       // [3][S] MLP out
    __shared__ float4 lw1i[HID];     // {W1 row, b1} interleaved (4 KB)
    __shared__ float4 lw2i[HID];     // {W2 cols} interleaved (4 KB)

    const int tid  = threadIdx.x;
    const int lane = tid & 63;
    const int wid  = tid >> 6;
    const int g    = blockIdx.x * WPB + wid;
    const float dt = dtp[0];
    const float invdt3 = 1.0f / (3.0f * dt);
    const int base = g * K + M * lane;

    // ---- preload MLP weight tables into LDS (off critical path; used at phase 2)
    if (tid < HID) {
        int h = tid;
        lw1i[h] = float4{ W1[3*h], W1[3*h + 1], W1[3*h + 2], b1v[h] };
    } else if (tid < 2 * HID) {
        int h = tid - HID;
        lw2i[h] = float4{ W2[h], W2[HID + h], W2[2*HID + h], 0.f };
    }

    float a[9], as[9];
#pragma unroll
    for (int i = 0; i < 9; ++i) { a[i] = Am[i]; as[i] = C2LE * Am[i]; }

    // build w for this wave's slice in registers (once, reused by all 3 phases)
    float4 ua0 = *(const float4*)(u + base);
    float4 ua1 = *(const float4*)(u + base + 4);
    float4 ub0 = *(const float4*)(u + SEQ_LEN + base);
    float4 ub1 = *(const float4*)(u + SEQ_LEN + base + 4);
    float4 uc0 = *(const float4*)(u + 2 * SEQ_LEN + base);
    float4 uc1 = *(const float4*)(u + 2 * SEQ_LEN + base + 4);
    float B0 = Bm[0], B1 = Bm[1], B2 = Bm[2], B3 = Bm[3], B4 = Bm[4],
          B5 = Bm[5], B6 = Bm[6], B7 = Bm[7], B8 = Bm[8];
    float ba0 = bAp[0], ba1 = bAp[1], ba2 = bAp[2];
    float U0[M] = { ua0.x, ua0.y, ua0.z, ua0.w, ua1.x, ua1.y, ua1.z, ua1.w };
    float U1[M] = { ub0.x, ub0.y, ub0.z, ub0.w, ub1.x, ub1.y, ub1.z, ub1.w };
    float U2[M] = { uc0.x, uc0.y, uc0.z, uc0.w, uc1.x, uc1.y, uc1.z, uc1.w };
    float w0[M], w1[M], w2[M];
#pragma unroll
    for (int i = 0; i < M; ++i) {
        w0[i] = C2LE * fmaf(B0, U0[i], fmaf(B1, U1[i], fmaf(B2, U2[i], ba0)));
        w1[i] = C2LE * fmaf(B3, U0[i], fmaf(B4, U1[i], fmaf(B5, U2[i], ba1)));
        w2[i] = C2LE * fmaf(B6, U0[i], fmaf(B7, U1[i], fmaf(B8, U2[i], ba2)));
    }

    float xk0[8], xk1[8], xk2[8];    // phase1 -> phase2 corrected-start carry
    shoot_phase<0>(lane, g, base, dt, invdt3, a, as, w0, w1, w2,
                   nullptr, jfA, xk0, xk1, xk2, nullptr, nullptr, nullptr, nullptr, nullptr);
    gbar(ctr, NB);                   // all phase-0 jfA coherent-visible
    shoot_phase<1>(lane, g, base, dt, invdt3, a, as, w0, w1, w2,
                   jfA, jfB, xk0, xk1, xk2, nullptr, nullptr, nullptr, nullptr, nullptr);
    gbar(ctr, 2 * NB);               // all phase-1 jfB coherent-visible
    shoot_phase<2>(lane, g, base, dt, invdt3, a, as, w0, w1, w2,
                   jfB, nullptr, xk0, xk1, xk2, xs, lw1i, lw2i, b2v, out);
}

extern "C" void kernel_launch(void* const* d_in, const int* in_sizes, int n_in,
                              void* d_out, int out_size, void* d_ws, size_t ws_size,
                              hipStream_t stream) {
    const float* u  = (const float*)d_in[0];
    const float* dt = (const float*)d_in[1];
    const float* A  = (const float*)d_in[2];
    const float* B  = (const float*)d_in[3];
    const float* bA = (const float*)d_in[4];
    const float* W1 = (const float*)d_in[5];
    const float* b1 = (const float*)d_in[6];
    const float* W2 = (const float*)d_in[7];
    const float* b2 = (const float*)d_in[8];

    float* out  = (float*)d_out;
    float* memb = out + 3 * SEQ_LEN;

    float4* jfA = (float4*)d_ws;        // [NG*3] 24.6 KB
    float4* jfB = jfA + 3 * NG;         // [NG*3] 24.6 KB
    unsigned* ctr = (unsigned*)(jfB + 3 * NG);

    // zero the barrier counter (stream-ordered, graph-capturable)
    hipMemsetAsync(ctr, 0, 64, stream);

    shoot_fused_mlp<<<NB, 512, 0, stream>>>(u, A, dt, B, bA, W1, b1, W2, b2,
                                            jfA, jfB, ctr, memb, out);
}

// Round 8
// 134.488 us; speedup vs baseline: 1.2616x; 1.2616x over previous
//
#include <hip/hip_runtime.h>

#define SEQ_LEN 262144
#define K 512                      // steps per group (one wave per group)
#define M 8                        // steps per lane
#define NG (SEQ_LEN / K)           // 512 groups
#define HID 256
#define C2LE 2.885390081777927f    // 2*log2(e)
// NCORR structure fixed at 2: phase0 (first shoot), phase1 (correct+shoot), phase2 (correct+shoot+store)
// (NCORR=1 FAILS: absmax 3.6e-2 measured in prior session R11)
//
// R2: cg::grid.sync + per-wave __threadfence = ~200us L2 maintenance storm.
// R3: launch_bounds(256,2) -> 128-VGPR cap -> scratch spill; coop launch +95us.
// R4: 512x64 + sc1 exchange + counter barrier -> 76us kernel, VALUBusy 5%.
// R5: backoff polling + 8B jf + fused MLP -> 82us kernel, 168 VGPR, no spill.
//     Residual ~60us = ARRIVAL serialization: 512 same-line atomic RMWs x
//     ~140cyc x 2 barriers (unchanged under 30x poll-pressure reduction).
// R6/R7: 8-wave blocks to cut arrivals -> hipcc capped VGPR at 128 under BOTH
//     __launch_bounds__(512) and (512,2) -> spill returned (WRITE 16.4MB vs
//     6.4MB real) -> 104-117us. launch-bounds semantics unverifiable; abandon.
// R8: back to the PROVEN no-spill config (64-thr blocks, 168 VGPR) + replace
//     the counter barrier with a FLAG-ARRAY barrier: arrive = one sc1 STORE
//     (no RMW -> no serialization), poll = 4 coalesced 8B sc1 loads/lane
//     sweeping all 512 flags. Expected ~2-4us/barrier vs ~30.

// ---------- DPP helpers ----------
template <int CTRL, int RM>
__device__ __forceinline__ float dpp_mov(float oldv, float v) {
    return __builtin_bit_cast(float, __builtin_amdgcn_update_dpp(
        __builtin_bit_cast(int, oldv), __builtin_bit_cast(int, v), CTRL, RM, 0xf, false));
}
template <int CTRL, int RM>
__device__ __forceinline__ float dpp_add(float v) {
    return v + dpp_mov<CTRL, RM>(0.0f, v);
}
__device__ __forceinline__ float wave_incl_scan(float v) {
    v = dpp_add<0x111, 0xf>(v);
    v = dpp_add<0x112, 0xf>(v);
    v = dpp_add<0x114, 0xf>(v);
    v = dpp_add<0x118, 0xf>(v);
    v = dpp_add<0x142, 0xa>(v);
    v = dpp_add<0x143, 0xc>(v);
    return v;
}
// full-wave shift right by 1 (lane i <- lane i-1; lane 0 <- 0)
__device__ __forceinline__ float dpp_wshr1(float v) {
    return __builtin_bit_cast(float, __builtin_amdgcn_update_dpp(
        0, __builtin_bit_cast(int, v), 0x138, 0xf, 0xf, false));
}
__device__ __forceinline__ float readlane_f(float v, int lane) {
    return __builtin_bit_cast(
        float, __builtin_amdgcn_readlane(__builtin_bit_cast(int, v), lane));
}

// ---------- agent-scope coherent access (sc1 -> LLC-coherent, bypasses per-XCD L2) ----------
typedef unsigned long long u64t;
__device__ __forceinline__ float2 coh_load_f2(const float* p) {
    u64t v = __hip_atomic_load((const u64t*)p, __ATOMIC_RELAXED, __HIP_MEMORY_SCOPE_AGENT);
    return __builtin_bit_cast(float2, v);
}
__device__ __forceinline__ void coh_store_f2(float* p, float a, float b) {
    float2 t{a, b};
    __hip_atomic_store((u64t*)p, __builtin_bit_cast(u64t, t),
                       __ATOMIC_RELAXED, __HIP_MEMORY_SCOPE_AGENT);
}

// ---------- flag-array grid barrier (no atomic RMW anywhere) ----------
// flags[NG] zeroed per launch by hipMemsetAsync. Arrival: after vmcnt(0)
// drains this block's sc1 jf stores to the LLC, lane 0 STORES flags[g]=phase
// (plain agent-scope store -> no RMW serialization; 512 stores spread over 32
// lines absorb in parallel). Poll: each lane sweeps 8 flags via 4 coalesced
// 8B agent-scope loads (lane L, chunk j -> flags[j*128 + 2L]), so one wave
// covers all 512 flags per round; __all() gates the exit. flag>=phase implies
// the writer's jf data is LLC-visible (store issued after its vmcnt drain).
__device__ __forceinline__ void gbar(unsigned* flags, int g, unsigned phase) {
    asm volatile("s_waitcnt vmcnt(0) lgkmcnt(0)" ::: "memory");
    const int lane = threadIdx.x;
    if (lane == 0)
        __hip_atomic_store(flags + g, phase, __ATOMIC_RELAXED, __HIP_MEMORY_SCOPE_AGENT);
    const u64t* p = (const u64t*)flags;
    for (;;) {
        u64t a = __hip_atomic_load(p + lane,        __ATOMIC_RELAXED, __HIP_MEMORY_SCOPE_AGENT);
        u64t b = __hip_atomic_load(p + 64 + lane,   __ATOMIC_RELAXED, __HIP_MEMORY_SCOPE_AGENT);
        u64t c = __hip_atomic_load(p + 128 + lane,  __ATOMIC_RELAXED, __HIP_MEMORY_SCOPE_AGENT);
        u64t d = __hip_atomic_load(p + 192 + lane,  __ATOMIC_RELAXED, __HIP_MEMORY_SCOPE_AGENT);
        unsigned m0 = (unsigned)a; m0 = min(m0, (unsigned)(a >> 32));
        unsigned m1 = (unsigned)b; m1 = min(m1, (unsigned)(b >> 32));
        unsigned m2 = (unsigned)c; m2 = min(m2, (unsigned)(c >> 32));
        unsigned m3 = (unsigned)d; m3 = min(m3, (unsigned)(d >> 32));
        unsigned mn = min(min(m0, m1), min(m2, m3));
        if (__all(mn >= phase)) break;
        __builtin_amdgcn_s_sleep(4);
    }
    asm volatile("" ::: "memory");   // keep jf loads after the poll exit
}

// ---------- affine map (3x3 M, 3 b) ----------
struct Aff { float m[9]; float b[3]; };

// r = n ∘ o  (apply o first, then n)
__device__ __forceinline__ void compose(Aff& r, const Aff& n, const Aff& o) {
#pragma unroll
    for (int i = 0; i < 3; ++i) {
#pragma unroll
        for (int j = 0; j < 3; ++j)
            r.m[3*i+j] = fmaf(n.m[3*i+0], o.m[0+j],
                         fmaf(n.m[3*i+1], o.m[3+j],
                              n.m[3*i+2] * o.m[6+j]));
        r.b[i] = fmaf(n.m[3*i+0], o.b[0],
                 fmaf(n.m[3*i+1], o.b[1],
                 fmaf(n.m[3*i+2], o.b[2], n.b[i])));
    }
}

template <int CTRL, int RM>
__device__ __forceinline__ void scan_level(Aff& a) {
    Aff p;
    p.m[0] = dpp_mov<CTRL, RM>(1.f, a.m[0]);
    p.m[1] = dpp_mov<CTRL, RM>(0.f, a.m[1]);
    p.m[2] = dpp_mov<CTRL, RM>(0.f, a.m[2]);
    p.m[3] = dpp_mov<CTRL, RM>(0.f, a.m[3]);
    p.m[4] = dpp_mov<CTRL, RM>(1.f, a.m[4]);
    p.m[5] = dpp_mov<CTRL, RM>(0.f, a.m[5]);
    p.m[6] = dpp_mov<CTRL, RM>(0.f, a.m[6]);
    p.m[7] = dpp_mov<CTRL, RM>(0.f, a.m[7]);
    p.m[8] = dpp_mov<CTRL, RM>(1.f, a.m[8]);
    p.b[0] = dpp_mov<CTRL, RM>(0.f, a.b[0]);
    p.b[1] = dpp_mov<CTRL, RM>(0.f, a.b[1]);
    p.b[2] = dpp_mov<CTRL, RM>(0.f, a.b[2]);
    Aff r; compose(r, a, p); a = r;
}

// ===================================================================
// MODE: 0 = FIRST (x0=0, no correct, write jf)
//       1 = MID   (correct with xh_old==0, SAVE xh_new to xk regs, shoot, write jf)
//       2 = FINAL (correct from jf_r + xk regs, shoot, store xs, fused MLP -> out)
// xh carried in registers between phases: phase-1's correction scan computes
// ALL groups' corrected start states redundantly in every block, so phase-2's
// xh_old[g+1] is already in this lane's registers (bit-identical everywhere).
// ===================================================================
template <int MODE>
__device__ __forceinline__ void shoot_phase(
    const int lane, const int g, const int base,
    const float dt, const float invdt3,
    const float (&a)[9], const float (&as)[9],
    const float (&w0)[M], const float (&w1)[M], const float (&w2)[M],
    const float4* __restrict__ jf_r, float4* __restrict__ jf_w,
    float (&xk0)[8], float (&xk1)[8], float (&xk2)[8],
    float* __restrict__ xs,
    const float4* lw1i, const float4* lw2i,          // LDS weight tables (MODE 2)
    const float* __restrict__ b2v, float* __restrict__ out) {

    // ---- Newton correct (redundant per block) -> this group's start state ----
    float x0 = 0.f, x1 = 0.f, x2 = 0.f;
    if (MODE != 0) {
        float J[8][9], dv[8][3], xhn0[8], xhn1[8], xhn2[8];
#pragma unroll
        for (int i = 0; i < 8; ++i) {
            int gg = 8 * lane + i;
            // coherent 8B loads: written by blocks on other XCDs; also defeats
            // stale L2 lines from previous graph replays.
            const float* src = (const float*)(jf_r + 3 * gg);
            float2 v0 = coh_load_f2(src + 0), v1 = coh_load_f2(src + 2),
                   v2 = coh_load_f2(src + 4), v3 = coh_load_f2(src + 6),
                   v4 = coh_load_f2(src + 8), v5 = coh_load_f2(src + 10);
            J[i][0] = v0.x; J[i][1] = v0.y; J[i][2] = v1.x;
            J[i][3] = v1.y; J[i][4] = v2.x; J[i][5] = v2.y;
            J[i][6] = v3.x; J[i][7] = v3.y; J[i][8] = v4.x;
            float xn0 = 0.f, xn1 = 0.f, xn2 = 0.f;
            if (MODE == 2) { xn0 = xk0[i]; xn1 = xk1[i]; xn2 = xk2[i]; }
            xhn0[i] = xn0; xhn1[i] = xn1; xhn2[i] = xn2;
            dv[i][0] = v4.y - xn0;               // F_g - xh_old[g+1]
            dv[i][1] = v5.x - xn1;
            dv[i][2] = v5.y - xn2;
        }
        Aff c;
#pragma unroll
        for (int k = 0; k < 9; ++k) c.m[k] = J[0][k];
        c.b[0] = dv[0][0]; c.b[1] = dv[0][1]; c.b[2] = dv[0][2];
#pragma unroll
        for (int i = 1; i < 8; ++i) {
            Aff s;
#pragma unroll
            for (int k = 0; k < 9; ++k) s.m[k] = J[i][k];
            s.b[0] = dv[i][0]; s.b[1] = dv[i][1]; s.b[2] = dv[i][2];
            Aff r; compose(r, s, c); c = r;
        }
        scan_level<0x111, 0xf>(c);
        scan_level<0x112, 0xf>(c);
        scan_level<0x114, 0xf>(c);
        scan_level<0x118, 0xf>(c);
        scan_level<0x142, 0xa>(c);
        scan_level<0x143, 0xc>(c);
        float ce0 = dpp_wshr1(c.b[0]);           // e at group 8*lane
        float ce1 = dpp_wshr1(c.b[1]);
        float ce2 = dpp_wshr1(c.b[2]);
        // walk: e_{g+1} = d_g + J_g e_g ; xh_new[g+1] = xh_old[g+1] + e_{g+1}
#pragma unroll
        for (int i = 0; i < 8; ++i) {
            float n0 = fmaf(J[i][0], ce0, fmaf(J[i][1], ce1, fmaf(J[i][2], ce2, dv[i][0])));
            float n1 = fmaf(J[i][3], ce0, fmaf(J[i][4], ce1, fmaf(J[i][5], ce2, dv[i][1])));
            float n2 = fmaf(J[i][6], ce0, fmaf(J[i][7], ce1, fmaf(J[i][8], ce2, dv[i][2])));
            ce0 = n0; ce1 = n1; ce2 = n2;
            xhn0[i] += ce0; xhn1[i] += ce1; xhn2[i] += ce2;  // now xh_new[8l+i+1]
        }
        if (MODE == 1) {   // carry corrected start states to phase 2 in registers
#pragma unroll
            for (int i = 0; i < 8; ++i) { xk0[i] = xhn0[i]; xk1[i] = xhn1[i]; xk2[i] = xhn2[i]; }
        }
        // broadcast xh_new[g] to the whole wave (g>0; g==0 stays 0)
        if (g > 0) {
            const int tl = (g - 1) >> 3, idx = (g - 1) & 7;  // wave-uniform
            float p0 = xhn0[0], p1 = xhn1[0], p2 = xhn2[0];
#pragma unroll
            for (int i = 1; i < 8; ++i) {
                p0 = (idx == i) ? xhn0[i] : p0;
                p1 = (idx == i) ? xhn1[i] : p1;
                p2 = (idx == i) ? xhn2[i] : p2;
            }
            x0 = readlane_f(p0, tl);
            x1 = readlane_f(p1, tl);
            x2 = readlane_f(p2, tl);
        }
    }

    // ---- shoot body (validated scheme, unchanged math) ----
    float zc0 = fmaf(as[0], x0, fmaf(as[1], x1, as[2] * x2));
    float zc1 = fmaf(as[3], x0, fmaf(as[4], x1, as[5] * x2));
    float zc2 = fmaf(as[6], x0, fmaf(as[7], x1, as[8] * x2));

    float t0s[M][3], c1s[M][3];
    Aff acc;
#pragma unroll
    for (int i = 0; i < M; ++i) {
        float z[3] = { w0[i] + zc0, w1[i] + zc1, w2[i] + zc2 };
        float cb[3], cv[3];
#pragma unroll
        for (int c = 0; c < 3; ++c) {
            float e  = __builtin_amdgcn_exp2f(z[c]);
            float r  = __builtin_amdgcn_rcpf(e + 1.0f);
            float t  = fmaf(-2.0f, r, 1.0f);
            float b  = dt * t;
            float c1 = fmaf(-b, t, dt);
            t0s[i][c] = t; c1s[i][c] = c1;
            cb[c] = b; cv[c] = c1;
        }
        Aff s;
        s.m[0] = fmaf(cv[0], a[0], 1.f); s.m[1] = cv[0] * a[1]; s.m[2] = cv[0] * a[2];
        s.m[3] = cv[1] * a[3]; s.m[4] = fmaf(cv[1], a[4], 1.f); s.m[5] = cv[1] * a[5];
        s.m[6] = cv[2] * a[6]; s.m[7] = cv[2] * a[7]; s.m[8] = fmaf(cv[2], a[8], 1.f);
        s.b[0] = cb[0]; s.b[1] = cb[1]; s.b[2] = cb[2];
        if (i == 0) acc = s;
        else { Aff r; compose(r, s, acc); acc = r; }
    }

    scan_level<0x111, 0xf>(acc);
    scan_level<0x112, 0xf>(acc);
    scan_level<0x114, 0xf>(acc);
    scan_level<0x118, 0xf>(acc);
    scan_level<0x142, 0xa>(acc);
    scan_level<0x143, 0xc>(acc);

    float ds0 = dpp_wshr1(acc.b[0]);
    float ds1 = dpp_wshr1(acc.b[1]);
    float ds2 = dpp_wshr1(acc.b[2]);

    float d0 = ds0, d1 = ds1, d2 = ds2;
    float outv[M][3];
#pragma unroll
    for (int i = 0; i < M; ++i) {
        float zz0 = fmaf(a[0], d0, fmaf(a[1], d1, a[2] * d2));
        float zz1 = fmaf(a[3], d0, fmaf(a[4], d1, a[5] * d2));
        float zz2 = fmaf(a[6], d0, fmaf(a[7], d1, a[8] * d2));
        float zz[3] = { zz0, zz1, zz2 };
        float dd[3];
#pragma unroll
        for (int c = 0; c < 3; ++c) {
            float t   = t0s[i][c], cv = c1s[i][c];
            float cb  = dt * t;
            float cT2 = -(t * cv);
            float pc  = fmaf(-invdt3, cv, 0.66666667f * (t * t));
            float cT3 = cv * pc;
            dd[c] = fmaf(fmaf(fmaf(cT3, zz[c], cT2), zz[c], cv), zz[c], cb);
        }
        d0 += dd[0]; d1 += dd[1]; d2 += dd[2];
        outv[i][0] = d0; outv[i][1] = d1; outv[i][2] = d2;
    }

    float q0 = d0 - acc.b[0], q1 = d1 - acc.b[1], q2 = d2 - acc.b[2];
    float e0 = wave_incl_scan(q0) - q0;
    float e1 = wave_incl_scan(q1) - q1;
    float e2 = wave_incl_scan(q2) - q2;
    float cor0 = x0 + e0, cor1 = x1 + e1, cor2 = x2 + e2;

    if (MODE == 2) {
        // final membrane values for this lane's 8 steps (also the MLP inputs)
        float X0[M], X1[M], X2[M];
#pragma unroll
        for (int i = 0; i < M; ++i) {
            X0[i] = outv[i][0] + cor0;
            X1[i] = outv[i][1] + cor1;
            X2[i] = outv[i][2] + cor2;
        }
        *(float4*)&xs[base]                   = float4{ X0[0], X0[1], X0[2], X0[3] };
        *(float4*)&xs[base + 4]               = float4{ X0[4], X0[5], X0[6], X0[7] };
        *(float4*)&xs[SEQ_LEN + base]         = float4{ X1[0], X1[1], X1[2], X1[3] };
        *(float4*)&xs[SEQ_LEN + base + 4]     = float4{ X1[4], X1[5], X1[6], X1[7] };
        *(float4*)&xs[2 * SEQ_LEN + base]     = float4{ X2[0], X2[1], X2[2], X2[3] };
        *(float4*)&xs[2 * SEQ_LEN + base + 4] = float4{ X2[4], X2[5], X2[6], X2[7] };

        // ---- fused MLP on register data; weights from LDS float4 tables ----
        // (uniform h across lanes -> LDS broadcast reads, conflict-free)
        float O0[M], O1[M], O2[M];
#pragma unroll
        for (int i = 0; i < M; ++i) { O0[i] = 0.f; O1[i] = 0.f; O2[i] = 0.f; }
#pragma unroll 2
        for (int h = 0; h < HID; ++h) {
            float4 wb = lw1i[h];   // {W1[h][0], W1[h][1], W1[h][2], b1[h]}
            float4 qv = lw2i[h];   // {W2[0][h], W2[1][h], W2[2][h], 0}
#pragma unroll
            for (int i = 0; i < M; ++i) {
                float hv = fmaf(wb.x, X0[i], fmaf(wb.y, X1[i], fmaf(wb.z, X2[i], wb.w)));
                hv = fmaxf(hv, 0.f);
                O0[i] = fmaf(qv.x, hv, O0[i]);
                O1[i] = fmaf(qv.y, hv, O1[i]);
                O2[i] = fmaf(qv.z, hv, O2[i]);
            }
        }
        const float bb0 = b2v[0], bb1 = b2v[1], bb2 = b2v[2];
        *(float4*)&out[base]                   = float4{ O0[0]+bb0, O0[1]+bb0, O0[2]+bb0, O0[3]+bb0 };
        *(float4*)&out[base + 4]               = float4{ O0[4]+bb0, O0[5]+bb0, O0[6]+bb0, O0[7]+bb0 };
        *(float4*)&out[SEQ_LEN + base]         = float4{ O1[0]+bb1, O1[1]+bb1, O1[2]+bb1, O1[3]+bb1 };
        *(float4*)&out[SEQ_LEN + base + 4]     = float4{ O1[4]+bb1, O1[5]+bb1, O1[6]+bb1, O1[7]+bb1 };
        *(float4*)&out[2 * SEQ_LEN + base]     = float4{ O2[0]+bb2, O2[1]+bb2, O2[2]+bb2, O2[3]+bb2 };
        *(float4*)&out[2 * SEQ_LEN + base + 4] = float4{ O2[4]+bb2, O2[5]+bb2, O2[6]+bb2, O2[7]+bb2 };
    } else {
        if (lane == 63) {
            float F0 = outv[M-1][0] + cor0;
            float F1 = outv[M-1][1] + cor1;
            float F2 = outv[M-1][2] + cor2;
            float* dst = (float*)(jf_w + 3 * g);
            coh_store_f2(dst + 0,  acc.m[0], acc.m[1]);
            coh_store_f2(dst + 2,  acc.m[2], acc.m[3]);
            coh_store_f2(dst + 4,  acc.m[4], acc.m[5]);
            coh_store_f2(dst + 6,  acc.m[6], acc.m[7]);
            coh_store_f2(dst + 8,  acc.m[8], F0);
            coh_store_f2(dst + 10, F1, F2);
        }
    }
}

// ---------- single fused kernel: 512 blocks x 64 threads, plain launch ----------
// Proven no-spill config (R5: 168 VGPR). 512 single-wave blocks are trivially
// co-resident (2 blocks/CU; LDS 8KB/block << 160KB) -> barrier cannot deadlock.
__global__ __launch_bounds__(64) void shoot_fused_mlp(
    const float* __restrict__ u,     // [3][S]
    const float* __restrict__ Am,    // [3][3]
    const float* __restrict__ dtp,   // scalar
    const float* __restrict__ Bm,    // [3][3]
    const float* __restrict__ bAp,   // [3]
    const float* __restrict__ W1,    // [256][3]
    const float* __restrict__ b1v,   // [256]
    const float* __restrict__ W2,    // [3][256]
    const float* __restrict__ b2v,   // [3]
    float4* __restrict__ jfA,        // [NG*3]
    float4* __restrict__ jfB,        // [NG*3]
    unsigned* __restrict__ flags,    // [NG] barrier flags (memset 0 per launch)
    float* __restrict__ xs,          // [3][S] membrane out
    float* __restrict__ out) {       // [3][S] MLP out
    __shared__ float4 lw1i[HID];     // {W1 row, b1} interleaved (4 KB)
    __shared__ float4 lw2i[HID];     // {W2 cols} interleaved (4 KB)

    const int lane = threadIdx.x;
    const int g = blockIdx.x;
    const float dt = dtp[0];
    const float invdt3 = 1.0f / (3.0f * dt);
    const int base = g * K + M * lane;

    // ---- preload MLP weight tables into LDS (off critical path; used at phase 2)
#pragma unroll
    for (int j = 0; j < 4; ++j) {
        int h = lane + 64 * j;
        lw1i[h] = float4{ W1[3*h], W1[3*h + 1], W1[3*h + 2], b1v[h] };
        lw2i[h] = float4{ W2[h], W2[HID + h], W2[2*HID + h], 0.f };
    }

    float a[9], as[9];
#pragma unroll
    for (int i = 0; i < 9; ++i) { a[i] = Am[i]; as[i] = C2LE * Am[i]; }

    // build w for this block's slice in registers (once, reused by all 3 phases)
    float4 ua0 = *(const float4*)(u + base);
    float4 ua1 = *(const float4*)(u + base + 4);
    float4 ub0 = *(const float4*)(u + SEQ_LEN + base);
    float4 ub1 = *(const float4*)(u + SEQ_LEN + base + 4);
    float4 uc0 = *(const float4*)(u + 2 * SEQ_LEN + base);
    float4 uc1 = *(const float4*)(u + 2 * SEQ_LEN + base + 4);
    float B0 = Bm[0], B1 = Bm[1], B2 = Bm[2], B3 = Bm[3], B4 = Bm[4],
          B5 = Bm[5], B6 = Bm[6], B7 = Bm[7], B8 = Bm[8];
    float ba0 = bAp[0], ba1 = bAp[1], ba2 = bAp[2];
    float U0[M] = { ua0.x, ua0.y, ua0.z, ua0.w, ua1.x, ua1.y, ua1.z, ua1.w };
    float U1[M] = { ub0.x, ub0.y, ub0.z, ub0.w, ub1.x, ub1.y, ub1.z, ub1.w };
    float U2[M] = { uc0.x, uc0.y, uc0.z, uc0.w, uc1.x, uc1.y, uc1.z, uc1.w };
    float w0[M], w1[M], w2[M];
#pragma unroll
    for (int i = 0; i < M; ++i) {
        w0[i] = C2LE * fmaf(B0, U0[i], fmaf(B1, U1[i], fmaf(B2, U2[i], ba0)));
        w1[i] = C2LE * fmaf(B3, U0[i], fmaf(B4, U1[i], fmaf(B5, U2[i], ba1)));
        w2[i] = C2LE * fmaf(B6, U0[i], fmaf(B7, U1[i], fmaf(B8, U2[i], ba2)));
    }

    float xk0[8], xk1[8], xk2[8];    // phase1 -> phase2 corrected-start carry
    shoot_phase<0>(lane, g, base, dt, invdt3, a, as, w0, w1, w2,
                   nullptr, jfA, xk0, xk1, xk2, nullptr, nullptr, nullptr, nullptr, nullptr);
    gbar(flags, g, 1u);              // all phase-0 jfA coherent-visible
    shoot_phase<1>(lane, g, base, dt, invdt3, a, as, w0, w1, w2,
                   jfA, jfB, xk0, xk1, xk2, nullptr, nullptr, nullptr, nullptr, nullptr);
    gbar(flags, g, 2u);              // all phase-1 jfB coherent-visible
    shoot_phase<2>(lane, g, base, dt, invdt3, a, as, w0, w1, w2,
                   jfB, nullptr, xk0, xk1, xk2, xs, lw1i, lw2i, b2v, out);
}

extern "C" void kernel_launch(void* const* d_in, const int* in_sizes, int n_in,
                              void* d_out, int out_size, void* d_ws, size_t ws_size,
                              hipStream_t stream) {
    const float* u  = (const float*)d_in[0];
    const float* dt = (const float*)d_in[1];
    const float* A  = (const float*)d_in[2];
    const float* B  = (const float*)d_in[3];
    const float* bA = (const float*)d_in[4];
    const float* W1 = (const float*)d_in[5];
    const float* b1 = (const float*)d_in[6];
    const float* W2 = (const float*)d_in[7];
    const float* b2 = (const float*)d_in[8];

    float* out  = (float*)d_out;
    float* memb = out + 3 * SEQ_LEN;

    float4* jfA = (float4*)d_ws;        // [NG*3] 24.6 KB
    float4* jfB = jfA + 3 * NG;         // [NG*3] 24.6 KB
    unsigned* flags = (unsigned*)(jfB + 3 * NG);   // [NG] 2 KB

    // zero the barrier flags (stream-ordered, graph-capturable)
    hipMemsetAsync(flags, 0, NG * sizeof(unsigned), stream);

    shoot_fused_mlp<<<NG, 64, 0, stream>>>(u, A, dt, B, bA, W1, b1, W2, b2,
                                           jfA, jfB, flags, memb, out);
}